// Round 12
// baseline (229.100 us; speedup 1.0000x reference)
//
#include <hip/hip_runtime.h>
#include <stdint.h>

// Problem constants (fixed by the reference): P=8192, L=64, H=128.
#define PCNT 8192
#define LROW 64
#define HDIM 128
#define XSTR 136                    // x_lds k-stride (f16), 16B-aligned rows
#define W1STR 136                   // W1^T k-stride (K=128 + 8 pad)
#define W23STR 264                  // W2^T/W3^T k-stride (K=256 + 8 pad)
#define W1_ELEMS (128 * W1STR)      // 17408
#define W23_ELEMS (128 * W23STR)    // 33792
#define NWAVE 4                     // waves (= polylines) per block

typedef _Float16 f16;
typedef __attribute__((ext_vector_type(8))) _Float16 half8;
typedef __attribute__((ext_vector_type(4))) _Float16 half4v;
typedef __attribute__((ext_vector_type(2))) _Float16 half2v;
typedef __attribute__((ext_vector_type(4))) float f32x4;

#define MFMA16(A, B, C) __builtin_amdgcn_mfma_f32_16x16x32_f16((A), (B), (C), 0, 0, 0)

__device__ __forceinline__ half8 ldh8(const f16* p) {
  return *reinterpret_cast<const half8*>(p);
}

union PkU { uint32_t u; half2v h; };

__device__ __forceinline__ uint32_t pk2(float lo, float hi) {
  PkU a;
  a.h[0] = (f16)lo;
  a.h[1] = (f16)hi;
  return a.u;
}

__device__ __forceinline__ uint32_t pkmax(uint32_t a, uint32_t b) {
  uint32_t d;
  asm("v_pk_max_f16 %0, %1, %2" : "=v"(d) : "v"(a), "v"(b));
  return d;
}

// ---------------------------------------------------------------------------
// Prep: ws = 3 transposed fp16 weight buffers (fused-K layout):
//   buf0 @0:                 W1^T  [c][k], k<128 real, stride 136
//   buf1 @W1_ELEMS:          W2^T  [c][k], k<256 real (Wa2|Wb2), stride 264
//   buf2 @W1_ELEMS+W23_ELEMS W3^T  same, stride 264
// ---------------------------------------------------------------------------
__global__ void prep_weights(const float* __restrict__ W1,
                             const float* __restrict__ W2,
                             const float* __restrict__ W3,
                             f16* __restrict__ wt) {
  int idx = blockIdx.x * 256 + threadIdx.x;
  if (idx >= W1_ELEMS + 2 * W23_ELEMS) return;
  float v = 0.0f;
  if (idx < W1_ELEMS) {
    int c = idx / W1STR, k = idx - c * W1STR;
    if (k < 128) v = W1[k * 128 + c];
  } else {
    int rem = idx - W1_ELEMS;
    const float* W = (rem < W23_ELEMS) ? W2 : W3;
    if (rem >= W23_ELEMS) rem -= W23_ELEMS;
    int c = rem / W23STR, k = rem - c * W23STR;
    if (k < 256) v = W[k * 128 + c];
  }
  wt[idx] = (f16)v;
}

// ---------------------------------------------------------------------------
// Fused kernel, ZERO-BARRIER design: one WAVE owns one polyline end-to-end.
// Transposed-D (R3 lineage) with the wave covering ALL 8 column-tiles:
// acc[mt][ct], lane holds row m=(l&15), cols ct*16+(l>>4)*4+r. Consequences:
//  - LN stats: in-lane 32-value sum + xor16/xor32 — no cross-wave combine.
//  - x' and phi live in this wave's private LDS slice; within-wave LDS
//    ordering is hardware lgkmcnt — NO __syncthreads in the kernel.
//  - bx fragment reused across 8 ctiles (1 ds_read : 8 MFMA).
// Fused-K (K=256 on layers 1/2, phi fragment uniform -> rank-1 concat term).
// 4 independent waves/block share L1 for weight fragments. LDS 70.7 KB ->
// 2 blocks/CU; __launch_bounds__(256,2) -> 256-VGPR budget (body ~200).
// ---------------------------------------------------------------------------
__global__ __launch_bounds__(256, 2)
void fused_subgraph(const float* __restrict__ hs,
                    const int* __restrict__ lens,
                    const f16* __restrict__ wt,
                    const float* __restrict__ b1, const float* __restrict__ g1, const float* __restrict__ be1,
                    const float* __restrict__ b2, const float* __restrict__ g2, const float* __restrict__ be2,
                    const float* __restrict__ b3, const float* __restrict__ g3, const float* __restrict__ be3,
                    float* __restrict__ out) {
  __shared__ __align__(16) f16 x_lds[NWAVE][LROW * XSTR];  // 4 x 17408 B
  __shared__ __align__(16) f16 phib[NWAVE][HDIM];          // 4 x 256 B

  const int tid = threadIdx.x;
  const int wv = tid >> 6;         // wave -> polyline
  const int l = tid & 63;          // lane
  const int p = blockIdx.x * NWAVE + wv;

  int len = lens[p];
  len = (len < 1) ? 1 : (len > LROW ? LROW : len);
  const int mtiles = (len + 15) >> 4;  // 1..4 M-tiles actually needed

  const int l15 = l & 15;
  const int lg = l >> 4;               // lane group 0..3
  const int ko = lg * 8;               // k offset within a 32-k tile

  f16* xP = x_lds[wv];
  f16* phiP = phib[wv];

  // ---- stage this wave's polyline: rows [0,16*mtiles), fp32 -> fp16 ----
  {
    const float* hp = hs + (size_t)p * (LROW * HDIM);
    const int nIter = mtiles * 4;  // 64 lanes x 8 f32 = 4 rows per iter
    for (int it = 0; it < nIter; ++it) {
      int e = (it * 64 + l) * 8;
      int r = e >> 7, c = e & 127;
      float4 va = *reinterpret_cast<const float4*>(hp + e);
      float4 vb = *reinterpret_cast<const float4*>(hp + e + 4);
      half8 hv;
      hv[0] = (f16)va.x; hv[1] = (f16)va.y; hv[2] = (f16)va.z; hv[3] = (f16)va.w;
      hv[4] = (f16)vb.x; hv[5] = (f16)vb.y; hv[6] = (f16)vb.z; hv[7] = (f16)vb.w;
      *reinterpret_cast<half8*>(&xP[r * XSTR + c]) = hv;
    }
  }
  // no barrier: same wave produces and consumes (lgkmcnt ordering)

#pragma unroll
  for (int layer = 0; layer < 3; ++layer) {
    const float* gv  = (layer == 0) ? g1  : (layer == 1) ? g2  : g3;
    const float* bev = (layer == 0) ? be1 : (layer == 1) ? be2 : be3;
    const float* bv  = (layer == 0) ? b1  : (layer == 1) ? b2  : b3;
    const f16* wa = (layer == 0) ? wt
                   : (layer == 1) ? (wt + W1_ELEMS)
                                  : (wt + W1_ELEMS + W23_ELEMS);
    const int wstr = (layer == 0) ? W1STR : W23STR;
    const int kcN  = (layer == 0) ? 4 : 8;

    // ---- GEMM: acc[mt][ct] = bias + (x~ @ W~)^T, K = 128 or 256 ----
    f32x4 acc[4][8];
#pragma unroll
    for (int ct = 0; ct < 8; ++ct) {
      const float4 bl = *reinterpret_cast<const float4*>(bv + ct * 16 + lg * 4);
      f32x4 s;
      s[0] = bl.x; s[1] = bl.y; s[2] = bl.z; s[3] = bl.w;
#pragma unroll
      for (int mt = 0; mt < 4; ++mt) acc[mt][ct] = s;
    }
#pragma unroll
    for (int kc = 0; kc < 8; ++kc) {
      if (kc >= kcN) break;
      half8 bfrag[4];
      half8 ph;
      if (kc < 4) {
#pragma unroll
        for (int mt = 0; mt < 4; ++mt)
          if (mt < mtiles) bfrag[mt] = ldh8(&xP[(mt * 16 + l15) * XSTR + kc * 32 + ko]);
      } else {
        ph = ldh8(&phiP[(kc - 4) * 32 + ko]);  // uniform -> row-constant term
      }
#pragma unroll
      for (int ct = 0; ct < 8; ++ct) {
        half8 wf = ldh8(&wa[(ct * 16 + l15) * wstr + kc * 32 + ko]);
        if (kc < 4) {
#pragma unroll
          for (int mt = 0; mt < 4; ++mt)
            if (mt < mtiles) acc[mt][ct] = MFMA16(wf, bfrag[mt], acc[mt][ct]);
        } else {
#pragma unroll
          for (int mt = 0; mt < 4; ++mt)
            if (mt < mtiles) acc[mt][ct] = MFMA16(wf, ph, acc[mt][ct]);
        }
      }
    }

    // ---- LN stats fully in-wave: 32-value in-lane sum + xor16/xor32 ----
    float mu_[4], rs_[4];
#pragma unroll
    for (int mt = 0; mt < 4; ++mt) {
      if (mt < mtiles) {
        float s = 0.0f, q = 0.0f;
#pragma unroll
        for (int ct = 0; ct < 8; ++ct) {
          const f32x4 a = acc[mt][ct];
          s += (a[0] + a[1]) + (a[2] + a[3]);
          q = fmaf(a[0], a[0], q);
          q = fmaf(a[1], a[1], q);
          q = fmaf(a[2], a[2], q);
          q = fmaf(a[3], a[3], q);
        }
        s += __shfl_xor(s, 16); q += __shfl_xor(q, 16);
        s += __shfl_xor(s, 32); q += __shfl_xor(q, 32);
        float mu = s * (1.0f / 128.0f);
        float var = q * (1.0f / 128.0f) - mu * mu;
        mu_[mt] = mu;
        rs_[mt] = rsqrtf(var + 1e-5f);
      }
    }

    // ---- epilogue: normalize+relu, x' write (f16), masked packed row-max ----
    uint32_t pm[8][2];
#pragma unroll
    for (int ct = 0; ct < 8; ++ct) { pm[ct][0] = 0u; pm[ct][1] = 0u; }
#pragma unroll
    for (int ct = 0; ct < 8; ++ct) {
      const float4 gg = *reinterpret_cast<const float4*>(gv + ct * 16 + lg * 4);
      const float4 eb = *reinterpret_cast<const float4*>(bev + ct * 16 + lg * 4);
#pragma unroll
      for (int mt = 0; mt < 4; ++mt) {
        if (mt < mtiles) {
          const int row = mt * 16 + l15;
          const bool valid = row < len;
          const float mu = mu_[mt], rs = rs_[mt];
          float v0 = fmaxf((acc[mt][ct][0] - mu) * rs * gg.x + eb.x, 0.0f);
          float v1 = fmaxf((acc[mt][ct][1] - mu) * rs * gg.y + eb.y, 0.0f);
          float v2 = fmaxf((acc[mt][ct][2] - mu) * rs * gg.z + eb.z, 0.0f);
          float v3 = fmaxf((acc[mt][ct][3] - mu) * rs * gg.w + eb.w, 0.0f);
          if (layer < 2) {
            half4v h;
            h[0] = (f16)v0; h[1] = (f16)v1; h[2] = (f16)v2; h[3] = (f16)v3;
            *reinterpret_cast<half4v*>(&xP[row * XSTR + ct * 16 + lg * 4]) = h;
          }
          pm[ct][0] = pkmax(pm[ct][0], pk2(valid ? v0 : 0.0f, valid ? v1 : 0.0f));
          pm[ct][1] = pkmax(pm[ct][1], pk2(valid ? v2 : 0.0f, valid ? v3 : 0.0f));
        }
      }
    }
    // reduce over the 16 l15 lanes (rows) — packed f16 max, 4 levels
#pragma unroll
    for (int d = 1; d <= 8; d <<= 1) {
#pragma unroll
      for (int ct = 0; ct < 8; ++ct) {
        pm[ct][0] = pkmax(pm[ct][0], (uint32_t)__shfl_xor((int)pm[ct][0], d));
        pm[ct][1] = pkmax(pm[ct][1], (uint32_t)__shfl_xor((int)pm[ct][1], d));
      }
    }

    if (layer < 2) {
      if (l15 == 0) {  // phi for next layer (4 consecutive f16 per uint2)
#pragma unroll
        for (int ct = 0; ct < 8; ++ct)
          *reinterpret_cast<uint2*>(&phiP[ct * 16 + lg * 4]) =
              make_uint2(pm[ct][0], pm[ct][1]);
      }
      // no barrier: same wave reads phiP next layer (lgkmcnt ordering)
    } else {
      if (l15 == 0) {  // output = concat(phi3, phi3)
        float* op = out + (size_t)p * 256;
#pragma unroll
        for (int ct = 0; ct < 8; ++ct) {
          PkU q0, q1;
          q0.u = pm[ct][0]; q1.u = pm[ct][1];
          float4 o = make_float4((float)q0.h[0], (float)q0.h[1],
                                 (float)q1.h[0], (float)q1.h[1]);
          *reinterpret_cast<float4*>(op + ct * 16 + lg * 4) = o;
          *reinterpret_cast<float4*>(op + 128 + ct * 16 + lg * 4) = o;
        }
      }
    }
  }
}

extern "C" void kernel_launch(void* const* d_in, const int* in_sizes, int n_in,
                              void* d_out, int out_size, void* d_ws, size_t ws_size,
                              hipStream_t stream) {
  const float* hs  = (const float*)d_in[0];
  const int* lens  = (const int*)d_in[1];
  const float* W1  = (const float*)d_in[2];
  const float* b1  = (const float*)d_in[3];
  const float* g1  = (const float*)d_in[4];
  const float* be1 = (const float*)d_in[5];
  const float* W2  = (const float*)d_in[6];
  const float* b2  = (const float*)d_in[7];
  const float* g2  = (const float*)d_in[8];
  const float* be2 = (const float*)d_in[9];
  const float* W3  = (const float*)d_in[10];
  const float* b3  = (const float*)d_in[11];
  const float* g3  = (const float*)d_in[12];
  const float* be3 = (const float*)d_in[13];
  float* out = (float*)d_out;
  f16* wt = (f16*)d_ws;  // needs (17408 + 2*33792)*2 = 169984 B of scratch

  const int prep_total = W1_ELEMS + 2 * W23_ELEMS;
  prep_weights<<<(prep_total + 255) / 256, 256, 0, stream>>>(W1, W2, W3, wt);
  fused_subgraph<<<PCNT / NWAVE, 256, 0, stream>>>(hs, lens, wt,
                                                   b1, g1, be1, b2, g2, be2, b3, g3, be3,
                                                   out);
}